// Round 12
// baseline (213.708 us; speedup 1.0000x reference)
//
#include <hip/hip_runtime.h>
#include <hip/hip_bf16.h>
#include <stdint.h>

typedef unsigned short u16;
typedef __attribute__((ext_vector_type(8))) short short8;
typedef __attribute__((ext_vector_type(4))) float floatx4;

#define N_IMG 4
#define C_IN  2048
#define HW    1024
#define KK    9
#define O_OUT 256
#define NPIX  4096          // N_IMG*HW
#define M_PAD  2432         // 19*128 (2304 proj rows + 81 conv + pad)
#define K_DIM  2048
#define BN_EPS 1e-5f

// workspace offsets (bytes), 256-aligned
#define OFF_A    0u
#define OFF_XT   9961472u          // A: 2432*2048*2
#define OFF_H    26738688u         // XT: 4096*2048*2
#define OFF_SRAW 46661632u         // H: 2432*4096*2
#define OFF_STAT 46809088u         // sraw: 36864*4

// fp32 -> bf16 bits, round-to-nearest-even
__device__ __forceinline__ u16 f2b(float f) {
    unsigned u = __float_as_uint(f);
    return (u16)((u + 0x7FFFu + ((u >> 16) & 1u)) >> 16);
}

__device__ __forceinline__ void load8f(const float* base, size_t eidx, u16* out) {
    const float* p = base + eidx;
    float4 a = ((const float4*)p)[0];
    float4 b = ((const float4*)p)[1];
    float f[8] = {a.x, a.y, a.z, a.w, b.x, b.y, b.z, b.w};
#pragma unroll
    for (int j = 0; j < 8; ++j) out[j] = f2b(f[j]);
}

// ---------------- merged staging kernel (R10-validated) ----------------
__global__ void build_all(const float* __restrict__ x, const float* __restrict__ wgt,
                          const float* __restrict__ cw, u16* __restrict__ xt,
                          u16* __restrict__ A, float* __restrict__ stats) {
    __shared__ __align__(16) u16 lds[9 * 2056];
    int b = blockIdx.x, t = threadIdx.x;
    if (b < 2048) {
        int c0 = (b & 31) * 64, p0 = ((b >> 5) & 15) * 64, n = b >> 9;
        int rp = t >> 3;                // channel-pair 0..31
        int pv = (t & 7) * 8;           // pixel group
        u16 h0[8], h1[8];
        load8f(x, (size_t)(n * C_IN + c0 + 2 * rp) * HW + p0 + pv, h0);
        load8f(x, (size_t)(n * C_IN + c0 + 2 * rp + 1) * HW + p0 + pv, h1);
        unsigned* l32 = (unsigned*)lds;   // [64 pixels][stride 35 u32]
#pragma unroll
        for (int j = 0; j < 8; ++j)
            l32[(pv + j) * 35 + rp] = (unsigned)h0[j] | ((unsigned)h1[j] << 16);
        __syncthreads();
        int pr = t >> 3, cq = (t & 7) * 4;   // pixel, u32-quad (8 channels)
        unsigned o0[4], o1[4];
#pragma unroll
        for (int i = 0; i < 4; ++i) {
            o0[i] = l32[pr * 35 + cq + i];
            o1[i] = l32[(pr + 32) * 35 + cq + i];
        }
        *(uint4*)(xt + (size_t)(n * HW + p0 + pr) * K_DIM + c0 + cq * 2) = *(uint4*)o0;
        *(uint4*)(xt + (size_t)(n * HW + p0 + pr + 32) * K_DIM + c0 + cq * 2) = *(uint4*)o1;
    } else if (b < 2304) {
        int o = b - 2048;
        size_t base = (size_t)o * 18432;   // weight[o][c][l], e = c*9+l
        for (int i = 0; i < 9; ++i) {
            int e0 = (t + i * 256) * 8;
            u16 hv[8];
            load8f(wgt, base + e0, hv);
#pragma unroll
            for (int j = 0; j < 8; ++j) {
                int e = e0 + j;
                int c = e / 9, l = e - c * 9;
                lds[l * 2056 + c] = hv[j];
            }
        }
        __syncthreads();
        for (int l = 0; l < 9; ++l) {
            size_t row = (size_t)l * 256 + o;
            *(uint4*)(A + row * K_DIM + t * 8) = *(const uint4*)&lds[l * 2056 + t * 8];
        }
    } else if (b < 2313) {
        int l = b - 2304;
        size_t base = (size_t)l * 18432;    // conv_w[l][c][k], e = c*9+k
        for (int i = 0; i < 9; ++i) {
            int e0 = (t + i * 256) * 8;
            u16 hv[8];
            load8f(cw, base + e0, hv);
#pragma unroll
            for (int j = 0; j < 8; ++j) {
                int e = e0 + j;
                int c = e / 9, k = e - c * 9;
                lds[k * 2056 + c] = hv[j];
            }
        }
        __syncthreads();
        for (int k = 0; k < 9; ++k) {
            size_t row = 2304 + (size_t)k * 9 + l;
            *(uint4*)(A + row * K_DIM + t * 8) = *(const uint4*)&lds[k * 2056 + t * 8];
        }
    } else {
        uint4 z = {0, 0, 0, 0};
        uint4* dst = (uint4*)(A + (size_t)2385 * K_DIM);
        for (int i = t; i < (47 * 2048) / 8; i += 256) dst[i] = z;
        if (t < 18) stats[t] = 0.0f;
    }
}

// ---------------- GEMM: H = A * XT^T, 128x128 tiles, BK=64, fragment-order LDS (conflict-free) ----------------
__device__ __forceinline__ void gload_lds16(const void* g, void* l) {
    __builtin_amdgcn_global_load_lds((__attribute__((address_space(1))) void*)(g),
                                     (__attribute__((address_space(3))) void*)(l), 16, 0, 0);
}

__global__ void gemm_bt(const u16* __restrict__ A, const u16* __restrict__ B,
                        __hip_bfloat16* __restrict__ C) {
    // chunk = 512 u16 = one 16-row x 32-k block stored in MFMA fragment order:
    // u16 offset lane*8 holds row (lane&15), k-start (lane>>4)*8
    __shared__ __align__(16) u16 As[2 * 128 * 32];
    __shared__ __align__(16) u16 Bs[2 * 128 * 32];
    int bx = blockIdx.x;
    // XCD swizzle: consecutive bx round-robin across 8 XCDs; give each XCD a
    // contiguous tile range (76 tiles = 4 nt x 19 mt) so its 4 B-tiles fit L2.
    int tile = (bx >> 3) + (bx & 7) * 76;
    int mt = tile % 19, nt = tile / 19;
    int m0 = mt * 128, n0 = nt * 128;
    int t = threadIdx.x;
    int w = t >> 6, lam = t & 63;
    int wm = w >> 1, wn = w & 1;
    int lm = lam & 15, q = lam >> 4;

    floatx4 acc[4][4];
    floatx4 z = {0.f, 0.f, 0.f, 0.f};
#pragma unroll
    for (int i = 0; i < 4; ++i)
#pragma unroll
        for (int j = 0; j < 4; ++j) acc[i][j] = z;

    // staging: chunk c (0..15): ks = c>>3 (k-half), rc = c&7 (16-row block).
    // lane lam fetches row rc*16 + (lam&15), k = ks*32 + (lam>>4)*8  (fragment order)
    const u16* gA[4]; const u16* gB[4];
    u16* lA[4];       u16* lB[4];
#pragma unroll
    for (int ii = 0; ii < 4; ++ii) {
        int c = w * 4 + ii;         // 0..15
        int rc = c & 7, ks = c >> 3;
        gA[ii] = A + (size_t)(m0 + rc * 16 + lm) * K_DIM + ks * 32 + q * 8;
        gB[ii] = B + (size_t)(n0 + rc * 16 + lm) * K_DIM + ks * 32 + q * 8;
        lA[ii] = As + ks * 4096 + rc * 512;
        lB[ii] = Bs + ks * 4096 + rc * 512;
    }

    for (int kt = 0; kt < K_DIM / 64; ++kt) {
#pragma unroll
        for (int ii = 0; ii < 4; ++ii) {
            gload_lds16(gA[ii], lA[ii]);
            gload_lds16(gB[ii], lB[ii]);
            gA[ii] += 64; gB[ii] += 64;
        }
        __syncthreads();
#pragma unroll
        for (int ks = 0; ks < 2; ++ks) {
            short8 af[4], bf[4];
#pragma unroll
            for (int i = 0; i < 4; ++i)      // conflict-free: lane lam reads lam*8 within chunk
                af[i] = *(const short8*)(As + ks * 4096 + (wm * 4 + i) * 512 + lam * 8);
#pragma unroll
            for (int j = 0; j < 4; ++j)
                bf[j] = *(const short8*)(Bs + ks * 4096 + (wn * 4 + j) * 512 + lam * 8);
#pragma unroll
            for (int i = 0; i < 4; ++i)
#pragma unroll
                for (int j = 0; j < 4; ++j)
                    acc[i][j] = __builtin_amdgcn_mfma_f32_16x16x32_bf16(af[i], bf[j], acc[i][j], 0, 0, 0);
        }
        __syncthreads();
    }
    // C/D layout: col=lane&15, row=(lane>>4)*4+reg
#pragma unroll
    for (int i = 0; i < 4; ++i) {
        int gm = m0 + wm * 64 + i * 16 + q * 4;
#pragma unroll
        for (int j = 0; j < 4; ++j) {
            int gn = n0 + wn * 64 + j * 16 + lm;
#pragma unroll
            for (int r = 0; r < 4; ++r)
                C[(size_t)(gm + r) * NPIX + gn] = __float2bfloat16(acc[i][j][r]);
        }
    }
}

// ---------------- sigma_raw (conv rows of H) + BN stats (R7-validated) ----------------
__global__ void sigma_stats(const __hip_bfloat16* __restrict__ Hm, float* __restrict__ sraw,
                            float* __restrict__ stats) {
    int b = blockIdx.x;           // (n*9 + l)*4 + quarter
    int qq = b & 3, nl = b >> 2;
    int n = nl / 9, l = nl - n * 9;
    int t = threadIdx.x;
    int pix = qq * 256 + t;
    int y = pix >> 5, x = pix & 31;
    float v = 0.f;
#pragma unroll
    for (int k = 0; k < 9; ++k) {
        int yy = y + k / 3 - 1, xx = x + (k % 3) - 1;
        if (yy >= 0 && yy < 32 && xx >= 0 && xx < 32)
            v += __bfloat162float(Hm[(size_t)(2304 + k * 9 + l) * NPIX + n * HW + yy * 32 + xx]);
    }
    sraw[(size_t)nl * HW + pix] = v;
    __shared__ float r1[256], r2[256];
    r1[t] = v; r2[t] = v * v;
    __syncthreads();
    for (int s = 128; s > 0; s >>= 1) {
        if (t < s) { r1[t] += r1[t + s]; r2[t] += r2[t + s]; }
        __syncthreads();
    }
    if (t == 0) { atomicAdd(&stats[l], r1[0]); atomicAdd(&stats[9 + l], r2[0]); }
}

// ---------------- tail v3 (R11-validated): coalesced H reads, 2 o per block, pixel-halves ----------------
__global__ void tail(const __hip_bfloat16* __restrict__ Hm, const float* __restrict__ sraw,
                     const float* __restrict__ stats, const float* __restrict__ gamma,
                     const float* __restrict__ beta, float* __restrict__ out) {
    int b = blockIdx.x;
    int n = b >> 8, rem = b & 255;
    int ph = rem >> 7, og = rem & 127;
    int t = threadIdx.x;
    float mean[9], istd[9], gg[9], bb[9];
#pragma unroll
    for (int l = 0; l < 9; ++l) {
        float m = stats[l] * (1.f / 4096.f);
        float var = stats[9 + l] * (1.f / 4096.f) - m * m;
        mean[l] = m; istd[l] = rsqrtf(var + BN_EPS);
        gg[l] = gamma[l]; bb[l] = beta[l];
    }
    const __hip_bfloat16* hb = Hm + (size_t)(og * 2) * NPIX + (size_t)n * HW;
    float* ob = out + ((size_t)n * 256 + og * 2) * HW;
#pragma unroll
    for (int i = 0; i < 2; ++i) {
        int pix = ph * 512 + i * 256 + t;
        int y = pix >> 5, x = pix & 31;
        float v[9];
        float mx = -1e30f;
#pragma unroll
        for (int l = 0; l < 9; ++l) {
            float tv = (sraw[(size_t)(n * 9 + l) * HW + pix] - mean[l]) * istd[l];
            tv = tv * gg[l] + bb[l];
            v[l] = tv; mx = fmaxf(mx, tv);
        }
        float ssum = 0.f;
#pragma unroll
        for (int l = 0; l < 9; ++l) { v[l] = __expf(v[l] - mx); ssum += v[l]; }
        float inv = 1.f / ssum;
        float acc0 = 0.f, acc1 = 0.f;
#pragma unroll
        for (int l = 0; l < 9; ++l) {
            int dy = l / 3 - 1, dx = l % 3 - 1;
            int yy = y + dy, xx = x + dx;
            if (yy >= 0 && yy < 32 && xx >= 0 && xx < 32) {
                float sv = v[l] * inv;
                size_t hidx = (size_t)(l * 256) * NPIX + (size_t)(pix + dy * 32 + dx);
                acc0 += sv * __bfloat162float(hb[hidx]);
                acc1 += sv * __bfloat162float(hb[hidx + NPIX]);
            }
        }
        ob[pix] = acc0;
        ob[HW + pix] = acc1;
    }
}

extern "C" void kernel_launch(void* const* d_in, const int* in_sizes, int n_in,
                              void* d_out, int out_size, void* d_ws, size_t ws_size,
                              hipStream_t stream) {
    const float* x     = (const float*)d_in[0];
    const float* cw    = (const float*)d_in[1];
    const float* gamma = (const float*)d_in[2];
    const float* beta  = (const float*)d_in[3];
    const float* wgt   = (const float*)d_in[4];

    char* ws = (char*)d_ws;
    u16*   Abuf = (u16*)(ws + OFF_A);
    u16*   XT   = (u16*)(ws + OFF_XT);
    u16*   Hm   = (u16*)(ws + OFF_H);
    float* sraw = (float*)(ws + OFF_SRAW);
    float* stats= (float*)(ws + OFF_STAT);

    build_all<<<2314, 256, 0, stream>>>(x, wgt, cw, XT, Abuf, stats);
    gemm_bt<<<19 * 32, 256, 0, stream>>>(Abuf, XT, (__hip_bfloat16*)Hm);
    sigma_stats<<<N_IMG * KK * 4, 256, 0, stream>>>((const __hip_bfloat16*)Hm, sraw, stats);
    tail<<<1024, 256, 0, stream>>>((const __hip_bfloat16*)Hm, sraw, stats, gamma, beta, (float*)d_out);
}

// Round 13
// 184.334 us; speedup vs baseline: 1.1594x; 1.1594x over previous
//
#include <hip/hip_runtime.h>
#include <hip/hip_bf16.h>
#include <stdint.h>

typedef unsigned short u16;
typedef __attribute__((ext_vector_type(8))) short short8;
typedef __attribute__((ext_vector_type(4))) float floatx4;

#define N_IMG 4
#define C_IN  2048
#define HW    1024
#define KK    9
#define O_OUT 256
#define NPIX  4096          // N_IMG*HW
#define M_PAD  2432         // 19*128 (2304 proj rows + 81 conv + pad)
#define K_DIM  2048
#define BN_EPS 1e-5f

// A and XT are stored TILED in fragment order:
//   chunk(rt, ct) = 512 u16 at ((rt*64)+ct)*512; rt = row/16, ct = k/32
//   within chunk: pos lam*8+j  <->  row rt*16+(lam&15), k ct*32+(lam>>4)*8+j
// workspace offsets (bytes), 256-aligned
#define OFF_A    0u
#define OFF_XT   9961472u          // A: 2432*2048*2
#define OFF_H    26738688u         // XT: 4096*2048*2
#define OFF_SRAW 46661632u         // H: 2432*4096*2
#define OFF_STAT 46809088u         // sraw: 36864*4

// fp32 -> bf16 bits, round-to-nearest-even
__device__ __forceinline__ u16 f2b(float f) {
    unsigned u = __float_as_uint(f);
    return (u16)((u + 0x7FFFu + ((u >> 16) & 1u)) >> 16);
}

__device__ __forceinline__ void load8f(const float* base, size_t eidx, u16* out) {
    const float* p = base + eidx;
    float4 a = ((const float4*)p)[0];
    float4 b = ((const float4*)p)[1];
    float f[8] = {a.x, a.y, a.z, a.w, b.x, b.y, b.z, b.w};
#pragma unroll
    for (int j = 0; j < 8; ++j) out[j] = f2b(f[j]);
}

// tiled store address (u16 units) for 8 consecutive k starting at k0 (k0 % 8 == 0)
__device__ __forceinline__ size_t tiled_pos(int row, int k0) {
    int lam = (row & 15) + (((k0 & 31) >> 3) << 4);
    return ((size_t)(row >> 4) * 64 + (k0 >> 5)) * 512 + lam * 8;
}

// ---------------- merged staging kernel ----------------
// blocks [0,2048): transpose x -> XT (tiled fragment order)
// blocks [2048,2304): A proj rows; [2304,2313): A conv rows; 2313: zero-pad + stats
__global__ void build_all(const float* __restrict__ x, const float* __restrict__ wgt,
                          const float* __restrict__ cw, u16* __restrict__ xt,
                          u16* __restrict__ A, float* __restrict__ stats) {
    __shared__ __align__(16) u16 lds[9 * 2056];
    int b = blockIdx.x, t = threadIdx.x;
    if (b < 2048) {
        int c0 = (b & 31) * 64, p0 = ((b >> 5) & 15) * 64, n = b >> 9;
        int rp = t >> 3;                // channel-pair 0..31
        int pv = (t & 7) * 8;           // pixel group
        u16 h0[8], h1[8];
        load8f(x, (size_t)(n * C_IN + c0 + 2 * rp) * HW + p0 + pv, h0);
        load8f(x, (size_t)(n * C_IN + c0 + 2 * rp + 1) * HW + p0 + pv, h1);
        unsigned* l32 = (unsigned*)lds;   // [64 pixels][stride 35 u32]
#pragma unroll
        for (int j = 0; j < 8; ++j)
            l32[(pv + j) * 35 + rp] = (unsigned)h0[j] | ((unsigned)h1[j] << 16);
        __syncthreads();
        int pr = t >> 3, cq = (t & 7) * 4;   // pixel, u32-quad (8 channels)
        unsigned o0[4], o1[4];
#pragma unroll
        for (int i = 0; i < 4; ++i) {
            o0[i] = l32[pr * 35 + cq + i];
            o1[i] = l32[(pr + 32) * 35 + cq + i];
        }
        int row0 = n * HW + p0 + pr;
        int k0 = c0 + cq * 2;
        *(uint4*)(xt + tiled_pos(row0, k0))      = *(uint4*)o0;
        *(uint4*)(xt + tiled_pos(row0 + 32, k0)) = *(uint4*)o1;
    } else if (b < 2304) {
        int o = b - 2048;
        size_t base = (size_t)o * 18432;   // weight[o][c][l], e = c*9+l
        for (int i = 0; i < 9; ++i) {
            int e0 = (t + i * 256) * 8;
            u16 hv[8];
            load8f(wgt, base + e0, hv);
#pragma unroll
            for (int j = 0; j < 8; ++j) {
                int e = e0 + j;
                int c = e / 9, l = e - c * 9;
                lds[l * 2056 + c] = hv[j];
            }
        }
        __syncthreads();
        for (int l = 0; l < 9; ++l) {
            int row = l * 256 + o;
            *(uint4*)(A + tiled_pos(row, t * 8)) = *(const uint4*)&lds[l * 2056 + t * 8];
        }
    } else if (b < 2313) {
        int l = b - 2304;
        size_t base = (size_t)l * 18432;    // conv_w[l][c][k], e = c*9+k
        for (int i = 0; i < 9; ++i) {
            int e0 = (t + i * 256) * 8;
            u16 hv[8];
            load8f(cw, base + e0, hv);
#pragma unroll
            for (int j = 0; j < 8; ++j) {
                int e = e0 + j;
                int c = e / 9, k = e - c * 9;
                lds[k * 2056 + c] = hv[j];
            }
        }
        __syncthreads();
        for (int k = 0; k < 9; ++k) {
            int row = 2304 + k * 9 + l;
            *(uint4*)(A + tiled_pos(row, t * 8)) = *(const uint4*)&lds[k * 2056 + t * 8];
        }
    } else {
        uint4 z = {0, 0, 0, 0};
        for (int row = 2385; row < 2432; ++row)
            *(uint4*)(A + tiled_pos(row, t * 8)) = z;
        if (t < 18) stats[t] = 0.0f;
    }
}

// ---------------- GEMM: H = A * XT^T, 128x128 tiles, BK=64, tiled operands ----------------
// staging: 1 KB fully-contiguous per wave instruction; LDS in fragment order (0 conflicts)
__device__ __forceinline__ void gload_lds16(const void* g, void* l) {
    __builtin_amdgcn_global_load_lds((__attribute__((address_space(1))) void*)(g),
                                     (__attribute__((address_space(3))) void*)(l), 16, 0, 0);
}

__global__ void gemm_bt(const u16* __restrict__ A, const u16* __restrict__ B,
                        __hip_bfloat16* __restrict__ C) {
    __shared__ __align__(16) u16 As[2 * 128 * 32];
    __shared__ __align__(16) u16 Bs[2 * 128 * 32];
    int bx = blockIdx.x;
    // XCD swizzle (R12-validated: FETCH 118->78 MB): each XCD gets 76 contiguous tiles
    int tile = (bx >> 3) + (bx & 7) * 76;
    int mt = tile % 19, nt = tile / 19;
    int m0 = mt * 128, n0 = nt * 128;
    int t = threadIdx.x;
    int w = t >> 6, lam = t & 63;
    int wm = w >> 1, wn = w & 1;
    int lm = lam & 15, q = lam >> 4;

    floatx4 acc[4][4];
    floatx4 z = {0.f, 0.f, 0.f, 0.f};
#pragma unroll
    for (int i = 0; i < 4; ++i)
#pragma unroll
        for (int j = 0; j < 4; ++j) acc[i][j] = z;

    const u16* gA[4]; const u16* gB[4];
    u16* lA[4];       u16* lB[4];
#pragma unroll
    for (int ii = 0; ii < 4; ++ii) {
        int c = w * 4 + ii;         // 0..15
        int rc = c & 7, ks = c >> 3;
        gA[ii] = A + ((size_t)((m0 >> 4) + rc) * 64 + ks) * 512 + lam * 8;
        gB[ii] = B + ((size_t)((n0 >> 4) + rc) * 64 + ks) * 512 + lam * 8;
        lA[ii] = As + ks * 4096 + rc * 512;
        lB[ii] = Bs + ks * 4096 + rc * 512;
    }

    for (int kt = 0; kt < K_DIM / 64; ++kt) {
#pragma unroll
        for (int ii = 0; ii < 4; ++ii) {
            gload_lds16(gA[ii], lA[ii]);
            gload_lds16(gB[ii], lB[ii]);
            gA[ii] += 1024; gB[ii] += 1024;   // 2 k-tiles of 512 per BK=64 step
        }
        __syncthreads();
#pragma unroll
        for (int ks = 0; ks < 2; ++ks) {
            short8 af[4], bf[4];
#pragma unroll
            for (int i = 0; i < 4; ++i)      // conflict-free: lane lam reads lam*8 within chunk
                af[i] = *(const short8*)(As + ks * 4096 + (wm * 4 + i) * 512 + lam * 8);
#pragma unroll
            for (int j = 0; j < 4; ++j)
                bf[j] = *(const short8*)(Bs + ks * 4096 + (wn * 4 + j) * 512 + lam * 8);
#pragma unroll
            for (int i = 0; i < 4; ++i)
#pragma unroll
                for (int j = 0; j < 4; ++j)
                    acc[i][j] = __builtin_amdgcn_mfma_f32_16x16x32_bf16(af[i], bf[j], acc[i][j], 0, 0, 0);
        }
        __syncthreads();
    }
    // C/D layout: col=lane&15, row=(lane>>4)*4+reg
#pragma unroll
    for (int i = 0; i < 4; ++i) {
        int gm = m0 + wm * 64 + i * 16 + q * 4;
#pragma unroll
        for (int j = 0; j < 4; ++j) {
            int gn = n0 + wn * 64 + j * 16 + lm;
#pragma unroll
            for (int r = 0; r < 4; ++r)
                C[(size_t)(gm + r) * NPIX + gn] = __float2bfloat16(acc[i][j][r]);
        }
    }
}

// ---------------- sigma_raw (conv rows of H) + BN stats (R7-validated) ----------------
__global__ void sigma_stats(const __hip_bfloat16* __restrict__ Hm, float* __restrict__ sraw,
                            float* __restrict__ stats) {
    int b = blockIdx.x;           // (n*9 + l)*4 + quarter
    int qq = b & 3, nl = b >> 2;
    int n = nl / 9, l = nl - n * 9;
    int t = threadIdx.x;
    int pix = qq * 256 + t;
    int y = pix >> 5, x = pix & 31;
    float v = 0.f;
#pragma unroll
    for (int k = 0; k < 9; ++k) {
        int yy = y + k / 3 - 1, xx = x + (k % 3) - 1;
        if (yy >= 0 && yy < 32 && xx >= 0 && xx < 32)
            v += __bfloat162float(Hm[(size_t)(2304 + k * 9 + l) * NPIX + n * HW + yy * 32 + xx]);
    }
    sraw[(size_t)nl * HW + pix] = v;
    __shared__ float r1[256], r2[256];
    r1[t] = v; r2[t] = v * v;
    __syncthreads();
    for (int s = 128; s > 0; s >>= 1) {
        if (t < s) { r1[t] += r1[t + s]; r2[t] += r2[t + s]; }
        __syncthreads();
    }
    if (t == 0) { atomicAdd(&stats[l], r1[0]); atomicAdd(&stats[9 + l], r2[0]); }
}

// ---------------- tail v3 (R11-validated): coalesced H reads, 2 o per block, pixel-halves ----------------
__global__ void tail(const __hip_bfloat16* __restrict__ Hm, const float* __restrict__ sraw,
                     const float* __restrict__ stats, const float* __restrict__ gamma,
                     const float* __restrict__ beta, float* __restrict__ out) {
    int b = blockIdx.x;
    int n = b >> 8, rem = b & 255;
    int ph = rem >> 7, og = rem & 127;
    int t = threadIdx.x;
    float mean[9], istd[9], gg[9], bb[9];
#pragma unroll
    for (int l = 0; l < 9; ++l) {
        float m = stats[l] * (1.f / 4096.f);
        float var = stats[9 + l] * (1.f / 4096.f) - m * m;
        mean[l] = m; istd[l] = rsqrtf(var + BN_EPS);
        gg[l] = gamma[l]; bb[l] = beta[l];
    }
    const __hip_bfloat16* hb = Hm + (size_t)(og * 2) * NPIX + (size_t)n * HW;
    float* ob = out + ((size_t)n * 256 + og * 2) * HW;
#pragma unroll
    for (int i = 0; i < 2; ++i) {
        int pix = ph * 512 + i * 256 + t;
        int y = pix >> 5, x = pix & 31;
        float v[9];
        float mx = -1e30f;
#pragma unroll
        for (int l = 0; l < 9; ++l) {
            float tv = (sraw[(size_t)(n * 9 + l) * HW + pix] - mean[l]) * istd[l];
            tv = tv * gg[l] + bb[l];
            v[l] = tv; mx = fmaxf(mx, tv);
        }
        float ssum = 0.f;
#pragma unroll
        for (int l = 0; l < 9; ++l) { v[l] = __expf(v[l] - mx); ssum += v[l]; }
        float inv = 1.f / ssum;
        float acc0 = 0.f, acc1 = 0.f;
#pragma unroll
        for (int l = 0; l < 9; ++l) {
            int dy = l / 3 - 1, dx = l % 3 - 1;
            int yy = y + dy, xx = x + dx;
            if (yy >= 0 && yy < 32 && xx >= 0 && xx < 32) {
                float sv = v[l] * inv;
                size_t hidx = (size_t)(l * 256) * NPIX + (size_t)(pix + dy * 32 + dx);
                acc0 += sv * __bfloat162float(hb[hidx]);
                acc1 += sv * __bfloat162float(hb[hidx + NPIX]);
            }
        }
        ob[pix] = acc0;
        ob[HW + pix] = acc1;
    }
}

extern "C" void kernel_launch(void* const* d_in, const int* in_sizes, int n_in,
                              void* d_out, int out_size, void* d_ws, size_t ws_size,
                              hipStream_t stream) {
    const float* x     = (const float*)d_in[0];
    const float* cw    = (const float*)d_in[1];
    const float* gamma = (const float*)d_in[2];
    const float* beta  = (const float*)d_in[3];
    const float* wgt   = (const float*)d_in[4];

    char* ws = (char*)d_ws;
    u16*   Abuf = (u16*)(ws + OFF_A);
    u16*   XT   = (u16*)(ws + OFF_XT);
    u16*   Hm   = (u16*)(ws + OFF_H);
    float* sraw = (float*)(ws + OFF_SRAW);
    float* stats= (float*)(ws + OFF_STAT);

    build_all<<<2314, 256, 0, stream>>>(x, wgt, cw, XT, Abuf, stats);
    gemm_bt<<<19 * 32, 256, 0, stream>>>(Abuf, XT, (__hip_bfloat16*)Hm);
    sigma_stats<<<N_IMG * KK * 4, 256, 0, stream>>>((const __hip_bfloat16*)Hm, sraw, stats);
    tail<<<1024, 256, 0, stream>>>((const __hip_bfloat16*)Hm, sraw, stats, gamma, beta, (float*)d_out);
}